// Round 12
// baseline (1987.256 us; speedup 1.0000x reference)
//
#include <hip/hip_runtime.h>
#include <math.h>

typedef unsigned int uint;
typedef unsigned long long ull;
typedef unsigned short ushort;

#define DM   512
#define DS   128
#define TT   20
#define NL   4
#define NV   32000
#define NROW 2048

// ws layout (~10.4 MB)
#define OFF_A2  0u          // 4*128*64 float2  A2[l][j][i2] = (A[i2][j], A[i2+64][j])
#define OFF_B2  262144u     // 4*512*64 float2  B2[l][d][i2] = (B[i2][d], B[i2+64][d])
#define OFF_CT  1310720u    // 4*128*512 f32    Ct[l][j][d] = C[l][d][j]
#define OFF_X0  2359296u    // 2048*20*16 u32   spike masks ping (bit d&31 of word d>>5)
#define OFF_X1  4980736u    // 2621440          spike masks pong
#define OFF_H   7602176u    // 2048*20*4 u32    h masks
#define OFF_TIB 8257536u    // 2048*512 bf16    time-integrated

// d_out used as scratch (gemm fully overwrites it last):
// xf: [row][thalf][d][12] f32 (10 used + 2 pad) = 2048*2*512*12*4 = 100,663,296 B
// su: [row][t][lane] float2 = 2048*20*64*8 = 20,971,520 B
#define XF_FLOATS_PER_RT 6144u     // 512*12
#define SU_OFF_OUT 100663296u

typedef float f32x2 __attribute__((ext_vector_type(2)));
typedef float f32x4 __attribute__((ext_vector_type(4)));
typedef __bf16 bf16x8 __attribute__((ext_vector_type(8)));
typedef ushort us8 __attribute__((ext_vector_type(8)));

__device__ __forceinline__ ushort f2bf(float f){   // RNE f32->bf16
  uint x = __float_as_uint(f);
  uint r = x + 0x7fffu + ((x >> 16) & 1u);
  return (ushort)(r >> 16);
}

// ---------------- weight prep: paired A/B layouts + C transpose ----------------
__global__ __launch_bounds__(256) void bt_transpose_k(
    const float* __restrict__ A, const float* __restrict__ B, const float* __restrict__ C,
    float2* __restrict__ A2, float2* __restrict__ B2, float* __restrict__ Ct){
  int tid = blockIdx.x * 256 + threadIdx.x;
  int nth = gridDim.x * 256;
  for (int idx = tid; idx < 4*128*64; idx += nth){
    int l = idx >> 13, j = (idx >> 6) & 127, i = idx & 63;
    A2[idx] = make_float2(A[l*16384 + i*128 + j], A[l*16384 + (i+64)*128 + j]);
  }
  for (int idx = tid; idx < 4*512*64; idx += nth){
    int l = idx >> 15, d = (idx >> 6) & 511, i = idx & 63;
    B2[idx] = make_float2(B[l*65536 + i*512 + d], B[l*65536 + (i+64)*512 + d]);
  }
  for (int idx = tid; idx < 4*128*512; idx += nth){
    int l = idx >> 16, j = (idx >> 9) & 127, i = idx & 511;
    Ct[idx] = C[l*65536 + i*128 + j];
  }
}

// ---------------- temporal encode -> bitmasks + xf floats ----------------
__global__ __launch_bounds__(256) void enc_k(
    const int* __restrict__ ids, const float* __restrict__ emb,
    uint* __restrict__ X0, float* __restrict__ xf){
  int tid = threadIdx.x;
  int h = tid & 31, rloc = tid >> 5;
  int r = blockIdx.x * 8 + rloc;
  int id = ids[r];
  uint half = (uint)((rloc & 1) * 32);
  int kk[16];
  #pragma unroll
  for (int w = 0; w < 16; w++){
    float e    = emb[(size_t)id * DM + w*32 + h];
    float ex32 = (float)exp(-(double)e);     // correctly-rounded f32 exp(-x)
    float sg   = 1.0f / (1.0f + ex32);
    float p    = sg * 19.0f;
    int k = (int)floorf(p);
    if (k > TT-1) k = TT-1;
    kk[w] = k;
  }
  uint* Xr = X0 + (size_t)r * (TT*16);
  for (int t = 0; t < TT; t++){
    #pragma unroll
    for (int w = 0; w < 16; w++){
      uint bw = (uint)(__ballot(kk[w] == t) >> half);
      if (h == 0) Xr[t*16 + w] = bw;
    }
  }
  // xf floats: xf[r][thalf][d][tt] = (thalf*10+tt == k) ? 1 : 0
  #pragma unroll
  for (int w = 0; w < 16; w++){
    int d = w*32 + h;
    int k = kk[w];
    float* x0p = xf + ((size_t)r*2 + 0) * XF_FLOATS_PER_RT + d*12;
    float* x1p = xf + ((size_t)r*2 + 1) * XF_FLOATS_PER_RT + d*12;
    #define S1(t) (k==(t) ? 1.0f : 0.0f)
    *(float4*)(x0p)     = make_float4(S1(0),S1(1),S1(2),S1(3));
    *(float4*)(x0p + 4) = make_float4(S1(4),S1(5),S1(6),S1(7));
    *(float2*)(x0p + 8) = make_float2(S1(8),S1(9));
    *(float4*)(x1p)     = make_float4(S1(10),S1(11),S1(12),S1(13));
    *(float4*)(x1p + 4) = make_float4(S1(14),S1(15),S1(16),S1(17));
    *(float2*)(x1p + 8) = make_float2(S1(18),S1(19));
    #undef S1
  }
}

// ---------------- A1: B-phase su_pre = x @ B.T for 10 t per wave ----------------
// 1024 blocks x 256 thr = 4 waves = 2 rows x 2 t-halves -> 4096 waves (4/SIMD).
// fma(xf, b, acc) with xf in {0.0,1.0}: product exact -> identical to np's
// mul-then-add chain, ascending d, single accumulator per (t,i). Bit-exact.
__global__ __launch_bounds__(256) void snn_a1_k(
    int l, const float* __restrict__ xf, const float2* __restrict__ B2,
    float2* __restrict__ su){
  int tid = threadIdx.x;
  int lane = tid & 63, wv = tid >> 6;
  size_t r = (size_t)blockIdx.x * 2 + (wv >> 1);
  int th = wv & 1;
  const float*  xp = xf + (r*2 + th) * XF_FLOATS_PER_RT;
  const float2* Bl = B2 + l * 32768 + lane;

  f32x2 acc[10];
  #pragma unroll
  for (int t = 0; t < 10; t++) acc[t] = (f32x2){0.f, 0.f};

  #pragma unroll 2
  for (int db = 0; db < 512; db++){
    float2 b = Bl[db*64];
    f32x2 bb = {b.x, b.y};
    const float* xq = xp + db*12;
    float4 xa = *(const float4*)(xq);
    float4 xb = *(const float4*)(xq + 4);
    float2 xc = *(const float2*)(xq + 8);
    float xv[10] = {xa.x,xa.y,xa.z,xa.w, xb.x,xb.y,xb.z,xb.w, xc.x,xc.y};
    #pragma unroll
    for (int t = 0; t < 10; t++)
      acc[t] = __builtin_elementwise_fma((f32x2){xv[t], xv[t]}, bb, acc[t]);
  }
  float2* sp = su + (r*20 + th*10)*64 + lane;
  #pragma unroll
  for (int t = 0; t < 10; t++)
    sp[t*64] = make_float2(acc[t].x, acc[t].y);
}

// ---------------- A2: LIF1 recurrence over t -> H masks ----------------
// 512 blocks x 256 thr = 4 waves = 4 rows; A pairs in LDS (64 KB, 2 blocks/CU).
// No barriers in the t-loop; masks wave-uniform via ballot. Chain identical to
// all passing rounds: t1 (j ascending via m0 then m1) + su, LIF, hard reset.
__global__ __launch_bounds__(256) void snn_a2_k(
    int l, const float2* __restrict__ su, const float2* __restrict__ A2w,
    uint* __restrict__ H){
  __shared__ float2 As[128*64];    // As[j*64+i2] = (A[i2][j], A[i2+64][j])
  int tid = threadIdx.x;
  int lane = tid & 63, wv = tid >> 6;
  size_t r = (size_t)blockIdx.x * 4 + wv;

  { const float4* Ag = (const float4*)(A2w + l * 8192);
    float4* Asv = (float4*)As;
    #pragma unroll
    for (int p = 0; p < 16; p++) Asv[tid + p*256] = Ag[tid + p*256]; }
  __syncthreads();

  f32x2 sut[20];
  { const float2* sp = su + r*20*64 + lane;
    #pragma unroll
    for (int t = 0; t < TT; t++){ float2 v = sp[t*64]; sut[t] = (f32x2){v.x, v.y}; } }

  f32x2 v1 = {0.f, 0.f};
  ull m0 = 0, m1 = 0;
  #pragma unroll
  for (int t = 0; t < TT; t++){
    f32x2 t1 = {0.f, 0.f};
    #pragma unroll 4
    for (int j = 0; j < 64; j++){
      float sf = ((m0 >> j) & 1ull) ? 1.0f : 0.0f;
      float2 a = As[j*64 + lane];
      t1 = __builtin_elementwise_fma((f32x2){sf, sf}, (f32x2){a.x, a.y}, t1);
    }
    #pragma unroll 4
    for (int j = 0; j < 64; j++){
      float sf = ((m1 >> j) & 1ull) ? 1.0f : 0.0f;
      float2 a = As[(64 + j)*64 + lane];
      t1 = __builtin_elementwise_fma((f32x2){sf, sf}, (f32x2){a.x, a.y}, t1);
    }
    f32x2 s_ = t1 + sut[t];               // np: (h@A.T) + (x@B.T), one add per half
    v1 = v1 + (s_ - v1) * 0.5f;           // LIF, tau=2 (exact *0.5)
    bool sa = (v1.x >= 1.0f), sb = (v1.y >= 1.0f);
    if (sa) v1.x = 0.0f;                  // hard reset
    if (sb) v1.y = 0.0f;
    m0 = __ballot(sa);
    m1 = __ballot(sb);
    if (lane == 0)
      *(uint4*)(H + (r*TT + t)*4) =
        make_uint4((uint)m0, (uint)(m0 >> 32), (uint)m1, (uint)(m1 >> 32));
  }
}

// ---------------- kernel B: H@C.T then LIF2 -> X' + xf floats (bf16 ti last) ----------------
// r11 body; LIF2 t-loop now unrolled (acc stays in regs); writes next-layer xf.
__global__ __launch_bounds__(256, 4) void snn_b_k(
    int l, int last, const uint* __restrict__ Xin, const uint* __restrict__ Hg,
    const float* __restrict__ Ct, const float* __restrict__ Dfull,
    uint* __restrict__ Xout, ushort* __restrict__ tib, float* __restrict__ xfo){
  int tid = threadIdx.x;
  int lane = tid & 63, wv = tid >> 6;
  int rloc = wv >> 1, dgw = wv & 1;
  size_t r = (size_t)blockIdx.x * 2 + rloc;

  float acc[TT][4];
  #pragma unroll
  for (int t = 0; t < TT; t++){ acc[t][0]=0.f; acc[t][1]=0.f; acc[t][2]=0.f; acc[t][3]=0.f; }

  const float* Cl = Ct + l*65536 + dgw*256 + lane;
  const uint*  Hr = Hg + r * (TT*4);
  for (int jw = 0; jw < 4; jw++){
    uint sw[TT];
    #pragma unroll
    for (int t = 0; t < TT; t++)
      sw[t] = __builtin_amdgcn_readfirstlane(Hr[t*4 + jw]);
    #pragma unroll 4
    for (int jb = 0; jb < 32; jb++){
      const float* cp = Cl + (size_t)(jw*32 + jb) * 512;
      float c0 = cp[0], c1 = cp[64], c2 = cp[128], c3 = cp[192];
      #pragma unroll
      for (int t = 0; t < TT; t++){
        float sf = ((sw[t] >> jb) & 1u) ? 1.0f : 0.0f;
        acc[t][0] = fmaf(sf, c0, acc[t][0]);
        acc[t][1] = fmaf(sf, c1, acc[t][1]);
        acc[t][2] = fmaf(sf, c2, acc[t][2]);
        acc[t][3] = fmaf(sf, c3, acc[t][3]);
      }
    }
  }

  // LIF2 over t (unrolled: static acc indices, xf thalf/tt compile-time)
  float dv[4];
  #pragma unroll
  for (int k = 0; k < 4; k++) dv[k] = Dfull[l*DM + dgw*256 + k*64 + lane];
  float v2[4] = {0.f,0.f,0.f,0.f};
  int cnt[4] = {0,0,0,0};
  const uint* Xr = Xin + r * (TT*16) + dgw*8 + (lane >> 5);
  #pragma unroll
  for (int t = 0; t < TT; t++){
    bool s[4];
    #pragma unroll
    for (int k = 0; k < 4; k++){
      uint xw = Xr[t*16 + k*2];
      float t4 = ((xw >> (lane & 31)) & 1u) ? dv[k] : 0.0f;  // x_t * D
      float ou = acc[t][k] + t4;              // np: (h@C.T) + x*D, one add
      v2[k] = v2[k] + (ou - v2[k]) * 0.5f;
      s[k] = (v2[k] >= 1.0f);
      if (s[k]) v2[k] = 0.0f;
    }
    if (!last){
      #pragma unroll
      for (int k = 0; k < 4; k++){
        ull bm = __ballot(s[k]);
        if (lane == 0){
          Xout[(r*TT + t)*16 + dgw*8 + k*2]     = (uint)bm;
          Xout[(r*TT + t)*16 + dgw*8 + k*2 + 1] = (uint)(bm >> 32);
        }
        // next-layer xf float
        xfo[((size_t)r*2 + (t/10)) * XF_FLOATS_PER_RT
            + (size_t)(dgw*256 + k*64 + lane)*12 + (t%10)] = s[k] ? 1.0f : 0.0f;
      }
    } else {
      #pragma unroll
      for (int k = 0; k < 4; k++) cnt[k] += s[k] ? 1 : 0;
    }
  }
  if (last){
    #pragma unroll
    for (int k = 0; k < 4; k++)
      tib[r*DM + dgw*256 + k*64 + lane] = f2bf((float)cnt[k] / 20.0f);
  }
}

// ---------------- final projection: bf16 MFMA, BM=256 tile + XCD panel swizzle ----------------
__global__ __launch_bounds__(512, 2) void gemm_mfma_k(
    const ushort* __restrict__ tib, const float* __restrict__ Wp,
    const float* __restrict__ bp, float* __restrict__ out){
  __shared__ ushort lA[256*64];    // 32 KB
  __shared__ ushort lB[128*64];    // 16 KB
  int bid = blockIdx.x;
  int L = (bid & 7) * 250 + (bid >> 3);    // bijective on [0,2000)
  int m0 = (L & 7) * 256;
  int n0 = (L >> 3) * 128;
  int tid = threadIdx.x;
  int lane = tid & 63, wv = tid >> 6;      // 8 waves
  int wm = wv >> 1, wn = wv & 1;

  f32x4 acc[4][4];
  #pragma unroll
  for (int i = 0; i < 4; i++)
    #pragma unroll
    for (int j = 0; j < 4; j++) acc[i][j] = (f32x4){0.f,0.f,0.f,0.f};

  for (int k0 = 0; k0 < 512; k0 += 64){
    __syncthreads();
    #pragma unroll
    for (int i = 0; i < 4; i++){     // A: 256x64, global_load_lds 16B, pre-swizzled src
      int slot = tid + i*512; int row = slot >> 3; int cb8 = (slot & 7) * 8;
      int sc = cb8 ^ ((row & 7) * 8);
      const ushort* gp = tib + (size_t)(m0 + row) * 512 + k0 + sc;
      __builtin_amdgcn_global_load_lds((const __attribute__((address_space(1))) void*)gp,
          (__attribute__((address_space(3))) void*)&lA[slot*8], 16, 0, 0);
    }
    #pragma unroll
    for (int i = 0; i < 2; i++){     // B: 128x64, reg-stage f32 -> bf16, swizzled dest
      int slot = tid + i*512; int row = slot >> 3; int cb8 = (slot & 7) * 8;
      int sc = cb8 ^ ((row & 7) * 8);
      const float* gp = Wp + (size_t)(n0 + row) * 512 + k0 + sc;
      float4 u = *(const float4*)gp;
      float4 v = *(const float4*)(gp + 4);
      us8 pk;
      pk[0]=f2bf(u.x); pk[1]=f2bf(u.y); pk[2]=f2bf(u.z); pk[3]=f2bf(u.w);
      pk[4]=f2bf(v.x); pk[5]=f2bf(v.y); pk[6]=f2bf(v.z); pk[7]=f2bf(v.w);
      *(us8*)&lB[slot*8] = pk;
    }
    __syncthreads();
    #pragma unroll
    for (int kk = 0; kk < 2; kk++){
      bf16x8 af[4], bf_[4];
      int c = kk*32 + (lane >> 4) * 8;
      #pragma unroll
      for (int mi = 0; mi < 4; mi++){
        int row = wm*64 + mi*16 + (lane & 15);
        af[mi] = *(const bf16x8*)&lA[row*64 + (c ^ ((row & 7) * 8))];
      }
      #pragma unroll
      for (int ni = 0; ni < 4; ni++){
        int row = wn*64 + ni*16 + (lane & 15);
        bf_[ni] = *(const bf16x8*)&lB[row*64 + (c ^ ((row & 7) * 8))];
      }
      #pragma unroll
      for (int mi = 0; mi < 4; mi++)
        #pragma unroll
        for (int ni = 0; ni < 4; ni++)
          acc[mi][ni] = __builtin_amdgcn_mfma_f32_16x16x32_bf16(af[mi], bf_[ni], acc[mi][ni], 0, 0, 0);
    }
  }

  #pragma unroll
  for (int ni = 0; ni < 4; ni++){
    int col = n0 + wn*64 + ni*16 + (lane & 15);
    float bb = bp[col];
    #pragma unroll
    for (int mi = 0; mi < 4; mi++){
      int rbase_ = m0 + wm*64 + mi*16 + (lane >> 4) * 4;
      #pragma unroll
      for (int rr = 0; rr < 4; rr++)
        out[(size_t)(rbase_ + rr) * NV + col] = acc[mi][ni][rr] + bb;
    }
  }
}

extern "C" void kernel_launch(void* const* d_in, const int* in_sizes, int n_in,
                              void* d_out, int out_size, void* d_ws, size_t ws_size,
                              hipStream_t stream) {
  const int*   ids = (const int*)  d_in[0];
  const float* emb = (const float*)d_in[1];
  const float* A   = (const float*)d_in[2];
  const float* B   = (const float*)d_in[3];
  const float* C   = (const float*)d_in[4];
  const float* D   = (const float*)d_in[5];
  const float* Wp  = (const float*)d_in[6];
  const float* bp  = (const float*)d_in[7];
  float* out = (float*)d_out;
  char* ws = (char*)d_ws;
  float2* A2  = (float2*)(ws + OFF_A2);
  float2* B2  = (float2*)(ws + OFF_B2);
  float*  Ct  = (float*) (ws + OFF_CT);
  uint*   X0  = (uint*)  (ws + OFF_X0);
  uint*   X1  = (uint*)  (ws + OFF_X1);
  uint*   H   = (uint*)  (ws + OFF_H);
  ushort* tib = (ushort*)(ws + OFF_TIB);
  // d_out as scratch until the final gemm overwrite
  float*  xf  = (float*) ((char*)d_out);
  float2* su  = (float2*)((char*)d_out + SU_OFF_OUT);

  bt_transpose_k<<<dim3(512), dim3(256), 0, stream>>>(A, B, C, A2, B2, Ct);
  enc_k         <<<dim3(256), dim3(256), 0, stream>>>(ids, emb, X0, xf);
  for (int l = 0; l < NL; l++){
    uint* Xin  = (l & 1) ? X1 : X0;
    uint* Xout = (l & 1) ? X0 : X1;
    snn_a1_k<<<dim3(1024), dim3(256), 0, stream>>>(l, xf, B2, su);
    snn_a2_k<<<dim3(512),  dim3(256), 0, stream>>>(l, su, A2, H);
    snn_b_k <<<dim3(1024), dim3(256), 0, stream>>>(l, (l == NL-1) ? 1 : 0, Xin, H, Ct, D, Xout, tib, xf);
  }
  gemm_mfma_k<<<dim3(2000), dim3(512), 0, stream>>>(tib, Wp, bp, out);
}

// Round 13
// 1156.684 us; speedup vs baseline: 1.7181x; 1.7181x over previous
//
#include <hip/hip_runtime.h>
#include <math.h>

typedef unsigned int uint;
typedef unsigned long long ull;
typedef unsigned short ushort;

#define DM   512
#define DS   128
#define TT   20
#define NL   4
#define NV   32000
#define NROW 2048

// ws layout (~10.4 MB)
#define OFF_A2  0u          // 4*128*64 float2  A2[l][j][i2] = (A[i2][j], A[i2+64][j])
#define OFF_B2  262144u     // 4*512*64 float2  B2[l][d][i2] = (B[i2][d], B[i2+64][d])
#define OFF_CT  1310720u    // 4*128*512 f32    Ct[l][j][d] = C[l][d][j]
#define OFF_X0  2359296u    // 2048*20*16 u32   spike masks ping (bit d&31 of word d>>5)
#define OFF_X1  4980736u    // 2621440          spike masks pong
#define OFF_H   7602176u    // 2048*20*4 u32    h masks
#define OFF_TIB 8257536u    // 2048*512 bf16    time-integrated

typedef float f32x2 __attribute__((ext_vector_type(2)));
typedef float f32x4 __attribute__((ext_vector_type(4)));
typedef __bf16 bf16x8 __attribute__((ext_vector_type(8)));
typedef ushort us8 __attribute__((ext_vector_type(8)));

__device__ __forceinline__ ushort f2bf(float f){   // RNE f32->bf16
  uint x = __float_as_uint(f);
  uint r = x + 0x7fffu + ((x >> 16) & 1u);
  return (ushort)(r >> 16);
}

// ---------------- weight prep: paired A/B layouts + C transpose ----------------
__global__ __launch_bounds__(256) void bt_transpose_k(
    const float* __restrict__ A, const float* __restrict__ B, const float* __restrict__ C,
    float2* __restrict__ A2, float2* __restrict__ B2, float* __restrict__ Ct){
  int tid = blockIdx.x * 256 + threadIdx.x;
  int nth = gridDim.x * 256;
  for (int idx = tid; idx < 4*128*64; idx += nth){
    int l = idx >> 13, j = (idx >> 6) & 127, i = idx & 63;
    A2[idx] = make_float2(A[l*16384 + i*128 + j], A[l*16384 + (i+64)*128 + j]);
  }
  for (int idx = tid; idx < 4*512*64; idx += nth){
    int l = idx >> 15, d = (idx >> 6) & 511, i = idx & 63;
    B2[idx] = make_float2(B[l*65536 + i*512 + d], B[l*65536 + (i+64)*512 + d]);
  }
  for (int idx = tid; idx < 4*128*512; idx += nth){
    int l = idx >> 16, j = (idx >> 9) & 127, i = idx & 511;
    Ct[idx] = C[l*65536 + i*128 + j];
  }
}

// ---------------- temporal encode -> bitmasks (verified) ----------------
__global__ __launch_bounds__(256) void enc_k(
    const int* __restrict__ ids, const float* __restrict__ emb, uint* __restrict__ X0){
  int tid = threadIdx.x;
  int h = tid & 31, rloc = tid >> 5;
  int r = blockIdx.x * 8 + rloc;
  int id = ids[r];
  uint half = (uint)((rloc & 1) * 32);
  int kk[16];
  #pragma unroll
  for (int w = 0; w < 16; w++){
    float e    = emb[(size_t)id * DM + w*32 + h];
    float ex32 = (float)exp(-(double)e);     // correctly-rounded f32 exp(-x)
    float sg   = 1.0f / (1.0f + ex32);
    float p    = sg * 19.0f;
    int k = (int)floorf(p);
    if (k > TT-1) k = TT-1;
    kk[w] = k;
  }
  uint* Xr = X0 + (size_t)r * (TT*16);
  for (int t = 0; t < TT; t++){
    #pragma unroll
    for (int w = 0; w < 16; w++){
      uint bw = (uint)(__ballot(kk[w] == t) >> half);
      if (h == 0) Xr[t*16 + w] = bw;
    }
  }
}

// ---------------- kernel A: X@B.T (all t) then LIF1 recurrence -> H ----------------
// r9-verbatim structure (best measured): 256-thr block = 4 waves = 4 rows,
// bounds (256,2) -> VGPR 88, no spill, 2 blocks/CU. Row = 1 wave, 2 states/lane
// via pk_fma (independent IEEE halves -> bit-exact). breg[16] prefetch.
// Delta vs r9: recurrence j-loops unroll 8 (deeper ds_read batch ahead of the
// serial FMA chain).
__global__ __launch_bounds__(256, 2) void snn_a_k(
    int l, const uint* __restrict__ Xin, const float2* __restrict__ A2,
    const float2* __restrict__ B2, uint* __restrict__ H){
  __shared__ float2 As[128*64];    // 64 KB: As[j*64+i2] = (A[i2][j], A[i2+64][j])
  int tid  = threadIdx.x;
  int lane = tid & 63, wv = tid >> 6;
  size_t r = (size_t)blockIdx.x * 4 + wv;

  { // stage A layer slice (float4 coop loads)
    const float4* Ag = (const float4*)(A2 + l * 8192);
    float4* Asv = (float4*)As;
    #pragma unroll
    for (int p = 0; p < 16; p++) Asv[tid + p*256] = Ag[tid + p*256];
  }
  __syncthreads();

  const uint* Xr = Xin + r * (TT*16);
  f32x2 acc[TT];
  #pragma unroll
  for (int t = 0; t < TT; t++) acc[t] = (f32x2){0.f, 0.f};

  // ---- B-phase: acc[t] = (x[t] @ B.T)[i pair], d ascending (dw, g, u) ----
  const float2* Bl = B2 + l * 32768;
  for (int dw = 0; dw < 16; dw++){
    uint sw[TT];
    #pragma unroll
    for (int t = 0; t < TT; t++)
      sw[t] = __builtin_amdgcn_readfirstlane(Xr[t*16 + dw]);
    #pragma unroll
    for (int g = 0; g < 2; g++){
      f32x2 breg[16];                      // 16 loads in flight
      #pragma unroll
      for (int u = 0; u < 16; u++){
        float2 b = Bl[(dw*32 + g*16 + u) * 64 + lane];
        breg[u] = (f32x2){b.x, b.y};
      }
      #pragma unroll
      for (int u = 0; u < 16; u++){
        int db = g*16 + u;
        #pragma unroll
        for (int t = 0; t < TT; t++){
          float sf = ((sw[t] >> db) & 1u) ? 1.0f : 0.0f;   // wave-uniform
          acc[t] = __builtin_elementwise_fma((f32x2){sf, sf}, breg[u], acc[t]);
        }
      }
    }
  }

  // ---- LIF1 recurrence over t (t unrolled for static acc; j-loops rolled @8) ----
  f32x2 v1 = {0.f, 0.f};
  ull m0 = 0, m1 = 0;      // h masks: states 0-63 / 64-127 (wave-uniform)
  #pragma unroll
  for (int t = 0; t < TT; t++){
    f32x2 t1 = {0.f, 0.f};
    #pragma unroll 8
    for (int j = 0; j < 64; j++){
      float sf = ((m0 >> j) & 1ull) ? 1.0f : 0.0f;
      float2 a = As[j*64 + lane];
      t1 = __builtin_elementwise_fma((f32x2){sf, sf}, (f32x2){a.x, a.y}, t1);
    }
    #pragma unroll 8
    for (int j = 0; j < 64; j++){
      float sf = ((m1 >> j) & 1ull) ? 1.0f : 0.0f;
      float2 a = As[(64 + j)*64 + lane];
      t1 = __builtin_elementwise_fma((f32x2){sf, sf}, (f32x2){a.x, a.y}, t1);
    }
    f32x2 su = t1 + acc[t];               // np: (h@A.T) + (x@B.T), one add per half
    v1 = v1 + (su - v1) * 0.5f;           // LIF, tau=2 (exact *0.5 per half)
    bool sa = (v1.x >= 1.0f), sb = (v1.y >= 1.0f);
    if (sa) v1.x = 0.0f;                  // hard reset
    if (sb) v1.y = 0.0f;
    m0 = __ballot(sa);
    m1 = __ballot(sb);
    if (lane == 0)
      *(uint4*)(H + (r*TT + t)*4) =
        make_uint4((uint)m0, (uint)(m0 >> 32), (uint)m1, (uint)(m1 >> 32));
  }
}

// ---------------- kernel B: H@C.T then LIF2 -> X' (bf16 ti on last layer) ----------------
// r9 body + fully-unrolled LIF2 t-loop (static acc indices -> registers, no scratch).
__global__ __launch_bounds__(256, 4) void snn_b_k(
    int l, int last, const uint* __restrict__ Xin, const uint* __restrict__ Hg,
    const float* __restrict__ Ct, const float* __restrict__ Dfull,
    uint* __restrict__ Xout, ushort* __restrict__ tib){
  int tid = threadIdx.x;
  int lane = tid & 63, wv = tid >> 6;
  int rloc = wv >> 1, dgw = wv & 1;
  size_t r = (size_t)blockIdx.x * 2 + rloc;

  float acc[TT][4];
  #pragma unroll
  for (int t = 0; t < TT; t++){ acc[t][0]=0.f; acc[t][1]=0.f; acc[t][2]=0.f; acc[t][3]=0.f; }

  const float* Cl = Ct + l*65536 + dgw*256 + lane;
  const uint*  Hr = Hg + r * (TT*4);
  for (int jw = 0; jw < 4; jw++){
    uint sw[TT];
    #pragma unroll
    for (int t = 0; t < TT; t++)
      sw[t] = __builtin_amdgcn_readfirstlane(Hr[t*4 + jw]);
    #pragma unroll 4
    for (int jb = 0; jb < 32; jb++){
      const float* cp = Cl + (size_t)(jw*32 + jb) * 512;
      float c0 = cp[0], c1 = cp[64], c2 = cp[128], c3 = cp[192];
      #pragma unroll
      for (int t = 0; t < TT; t++){
        float sf = ((sw[t] >> jb) & 1u) ? 1.0f : 0.0f;
        acc[t][0] = fmaf(sf, c0, acc[t][0]);
        acc[t][1] = fmaf(sf, c1, acc[t][1]);
        acc[t][2] = fmaf(sf, c2, acc[t][2]);
        acc[t][3] = fmaf(sf, c3, acc[t][3]);
      }
    }
  }

  // LIF2 over t (fully unrolled)
  float dv[4];
  #pragma unroll
  for (int k = 0; k < 4; k++) dv[k] = Dfull[l*DM + dgw*256 + k*64 + lane];
  float v2[4] = {0.f,0.f,0.f,0.f};
  int cnt[4] = {0,0,0,0};
  const uint* Xr = Xin + r * (TT*16) + dgw*8 + (lane >> 5);
  #pragma unroll
  for (int t = 0; t < TT; t++){
    bool s[4];
    #pragma unroll
    for (int k = 0; k < 4; k++){
      uint xw = Xr[t*16 + k*2];
      float t4 = ((xw >> (lane & 31)) & 1u) ? dv[k] : 0.0f;  // x_t * D
      float ou = acc[t][k] + t4;              // np: (h@C.T) + x*D, one add
      v2[k] = v2[k] + (ou - v2[k]) * 0.5f;
      s[k] = (v2[k] >= 1.0f);
      if (s[k]) v2[k] = 0.0f;
    }
    if (!last){
      #pragma unroll
      for (int k = 0; k < 4; k++){
        ull bm = __ballot(s[k]);
        if (lane == 0){
          Xout[(r*TT + t)*16 + dgw*8 + k*2]     = (uint)bm;
          Xout[(r*TT + t)*16 + dgw*8 + k*2 + 1] = (uint)(bm >> 32);
        }
      }
    } else {
      #pragma unroll
      for (int k = 0; k < 4; k++) cnt[k] += s[k] ? 1 : 0;
    }
  }
  if (last){
    #pragma unroll
    for (int k = 0; k < 4; k++)
      tib[r*DM + dgw*256 + k*64 + lane] = f2bf((float)cnt[k] / 20.0f);
  }
}

// ---------------- final projection: bf16 MFMA, BM=256 tile + XCD panel swizzle ----------------
// 2000 blocks x 512 thr; block = 256 M x 128 N. Wp panel re-read/re-converted 8x
// (vs 16x at BM=128). bid%8 = XCD; each XCD owns ~31 consecutive panels.
__global__ __launch_bounds__(512, 2) void gemm_mfma_k(
    const ushort* __restrict__ tib, const float* __restrict__ Wp,
    const float* __restrict__ bp, float* __restrict__ out){
  __shared__ ushort lA[256*64];    // 32 KB
  __shared__ ushort lB[128*64];    // 16 KB
  int bid = blockIdx.x;
  int L = (bid & 7) * 250 + (bid >> 3);    // bijective on [0,2000)
  int m0 = (L & 7) * 256;
  int n0 = (L >> 3) * 128;
  int tid = threadIdx.x;
  int lane = tid & 63, wv = tid >> 6;      // 8 waves
  int wm = wv >> 1, wn = wv & 1;

  f32x4 acc[4][4];
  #pragma unroll
  for (int i = 0; i < 4; i++)
    #pragma unroll
    for (int j = 0; j < 4; j++) acc[i][j] = (f32x4){0.f,0.f,0.f,0.f};

  for (int k0 = 0; k0 < 512; k0 += 64){
    __syncthreads();
    #pragma unroll
    for (int i = 0; i < 4; i++){     // A: 256x64, global_load_lds 16B, pre-swizzled src
      int slot = tid + i*512; int row = slot >> 3; int cb8 = (slot & 7) * 8;
      int sc = cb8 ^ ((row & 7) * 8);
      const ushort* gp = tib + (size_t)(m0 + row) * 512 + k0 + sc;
      __builtin_amdgcn_global_load_lds((const __attribute__((address_space(1))) void*)gp,
          (__attribute__((address_space(3))) void*)&lA[slot*8], 16, 0, 0);
    }
    #pragma unroll
    for (int i = 0; i < 2; i++){     // B: 128x64, reg-stage f32 -> bf16, swizzled dest
      int slot = tid + i*512; int row = slot >> 3; int cb8 = (slot & 7) * 8;
      int sc = cb8 ^ ((row & 7) * 8);
      const float* gp = Wp + (size_t)(n0 + row) * 512 + k0 + sc;
      float4 u = *(const float4*)gp;
      float4 v = *(const float4*)(gp + 4);
      us8 pk;
      pk[0]=f2bf(u.x); pk[1]=f2bf(u.y); pk[2]=f2bf(u.z); pk[3]=f2bf(u.w);
      pk[4]=f2bf(v.x); pk[5]=f2bf(v.y); pk[6]=f2bf(v.z); pk[7]=f2bf(v.w);
      *(us8*)&lB[slot*8] = pk;
    }
    __syncthreads();
    #pragma unroll
    for (int kk = 0; kk < 2; kk++){
      bf16x8 af[4], bf_[4];
      int c = kk*32 + (lane >> 4) * 8;
      #pragma unroll
      for (int mi = 0; mi < 4; mi++){
        int row = wm*64 + mi*16 + (lane & 15);
        af[mi] = *(const bf16x8*)&lA[row*64 + (c ^ ((row & 7) * 8))];
      }
      #pragma unroll
      for (int ni = 0; ni < 4; ni++){
        int row = wn*64 + ni*16 + (lane & 15);
        bf_[ni] = *(const bf16x8*)&lB[row*64 + (c ^ ((row & 7) * 8))];
      }
      #pragma unroll
      for (int mi = 0; mi < 4; mi++)
        #pragma unroll
        for (int ni = 0; ni < 4; ni++)
          acc[mi][ni] = __builtin_amdgcn_mfma_f32_16x16x32_bf16(af[mi], bf_[ni], acc[mi][ni], 0, 0, 0);
    }
  }

  #pragma unroll
  for (int ni = 0; ni < 4; ni++){
    int col = n0 + wn*64 + ni*16 + (lane & 15);
    float bb = bp[col];
    #pragma unroll
    for (int mi = 0; mi < 4; mi++){
      int rbase_ = m0 + wm*64 + mi*16 + (lane >> 4) * 4;
      #pragma unroll
      for (int rr = 0; rr < 4; rr++)
        out[(size_t)(rbase_ + rr) * NV + col] = acc[mi][ni][rr] + bb;
    }
  }
}

extern "C" void kernel_launch(void* const* d_in, const int* in_sizes, int n_in,
                              void* d_out, int out_size, void* d_ws, size_t ws_size,
                              hipStream_t stream) {
  const int*   ids = (const int*)  d_in[0];
  const float* emb = (const float*)d_in[1];
  const float* A   = (const float*)d_in[2];
  const float* B   = (const float*)d_in[3];
  const float* C   = (const float*)d_in[4];
  const float* D   = (const float*)d_in[5];
  const float* Wp  = (const float*)d_in[6];
  const float* bp  = (const float*)d_in[7];
  float* out = (float*)d_out;
  char* ws = (char*)d_ws;
  float2* A2  = (float2*)(ws + OFF_A2);
  float2* B2  = (float2*)(ws + OFF_B2);
  float*  Ct  = (float*) (ws + OFF_CT);
  uint*   X0  = (uint*)  (ws + OFF_X0);
  uint*   X1  = (uint*)  (ws + OFF_X1);
  uint*   H   = (uint*)  (ws + OFF_H);
  ushort* tib = (ushort*)(ws + OFF_TIB);

  bt_transpose_k<<<dim3(512), dim3(256), 0, stream>>>(A, B, C, A2, B2, Ct);
  enc_k         <<<dim3(256), dim3(256), 0, stream>>>(ids, emb, X0);
  for (int l = 0; l < NL; l++){
    uint* Xin  = (l & 1) ? X1 : X0;
    uint* Xout = (l & 1) ? X0 : X1;
    snn_a_k<<<dim3(512),  dim3(256), 0, stream>>>(l, Xin, A2, B2, H);
    snn_b_k<<<dim3(1024), dim3(256), 0, stream>>>(l, (l == NL-1) ? 1 : 0, Xin, H, Ct, D, Xout, tib);
  }
  gemm_mfma_k<<<dim3(2000), dim3(512), 0, stream>>>(tib, Wp, bp, out);
}